// Round 1
// baseline (179.571 us; speedup 1.0000x reference)
//
#include <hip/hip_runtime.h>
#include <hip/hip_fp8.h>
#include <hip/hip_fp16.h>

// SumLayer: weighted logsumexp over E children per node.
// N=32768, E=32, B=256, MAX_ELS=65536.
//
// R4 design. Evidence: sum_main is L2-miss-bound (3.7 TB/s, dur ~ FETCH bytes).
// G=16MB > 4MB per-XCD L2 -> random gather misses ~75%. R2's XCD-slice attempt
// failed because G was row-major: a 32-col slice is 32B of every 128B line, so
// compulsory fetch stays 16MB/XCD regardless of affinity. Fix:
//   1) G stored CHUNK-MAJOR: G[chunk][row][32B], 8 contiguous 2MB slices.
//   2) chunk = blockIdx % 8  -> native round-robin block->XCD mapping gives
//      each XCD exactly one slice; compulsory G fetch = 16MB total.
//   3) cids fits u16 (MAX_ELS=2^16), W fits f16 -> packed u32 WC[N][E] (4MB);
//      per-XCD stream = 32MB total (was 64MB fp32).
// Predicted: sum_main FETCH ~337MB -> ~55MB, dur ~100us -> 15-25us.

constexpr int NN = 32768;
constexpr int EE = 32;
constexpr int BB = 256;
constexpr int MAX_ELS = 65536;

constexpr int NCHUNK = 8;                 // column chunks == XCD count
constexpr int CHUNK_COLS = 32;            // fp8 bytes per row per chunk
constexpr size_t SLICE_BYTES = (size_t)MAX_ELS * CHUNK_COLS;  // 2 MB
constexpr int NPB = 32;                   // nodes per block (main kernel)

typedef float floatx2 __attribute__((ext_vector_type(2)));

__device__ inline int pack4_fp8(float4 v) {
    const int a = __hip_cvt_float_to_fp8(__expf(v.x), __HIP_SATFINITE, __HIP_E4M3);
    const int b = __hip_cvt_float_to_fp8(__expf(v.y), __HIP_SATFINITE, __HIP_E4M3);
    const int c = __hip_cvt_float_to_fp8(__expf(v.z), __HIP_SATFINITE, __HIP_E4M3);
    const int d = __hip_cvt_float_to_fp8(__expf(v.w), __HIP_SATFINITE, __HIP_E4M3);
    return a | (b << 8) | (c << 16) | (d << 24);
}

// ---- pre-pass 1: G[chunk][r][0..31] = fp8(exp(element_mars[r][chunk*32+c])) ----
// thread i handles row r = i>>4, 16-col block cb = i&15 (chunk cb>>1, half cb&1).
__global__ __launch_bounds__(256)
void exp_convert_kernel(const float4* __restrict__ em, unsigned char* __restrict__ G)
{
    const int i  = blockIdx.x * 256 + threadIdx.x;
    const int r  = i >> 4;
    const int cb = i & 15;
    const float4 v0 = em[4*i+0], v1 = em[4*i+1], v2 = em[4*i+2], v3 = em[4*i+3];
    int4 o;
    o.x = pack4_fp8(v0);
    o.y = pack4_fp8(v1);
    o.z = pack4_fp8(v2);
    o.w = pack4_fp8(v3);
    *reinterpret_cast<int4*>(G + (size_t)(cb >> 1) * SLICE_BYTES
                               + (size_t)r * CHUNK_COLS + (cb & 1) * 16) = o;
}

// ---- pre-pass 2: WC[i] = (cids[i] as u16) | (f16(params[pids[i]]) << 16) ----
__global__ __launch_bounds__(256)
void pack_wc_kernel(const float* __restrict__ params, const int* __restrict__ cids,
                    const int* __restrict__ pids, unsigned int* __restrict__ WC)
{
    const int i = blockIdx.x * 256 + threadIdx.x;
    const unsigned int cid = (unsigned int)cids[i] & 0xFFFFu;   // MAX_ELS = 2^16
    const float w = params[pids[i]];
    const unsigned int h = (unsigned int)__half_as_ushort(__float2half(w));
    WC[i] = cid | (h << 16);
}

// ---- main: 32 nodes/block x 32 cols/block; chunk = blockIdx%8 -> XCD slice ----
__global__ __launch_bounds__(256)
void sum_main_kernel(const unsigned char* __restrict__ G, const unsigned int* __restrict__ WC,
                     const int* __restrict__ nids, float* __restrict__ out)
{
    const int chunk = blockIdx.x & (NCHUNK - 1);
    const int g     = blockIdx.x >> 3;          // node-group of 32
    const int tid   = threadIdx.x;

    // stage this group's packed (cid,w) entries; stride 33 kills the
    // 8-way same-bank broadcast conflict on the e-indexed reads.
    __shared__ unsigned int s_wc[NPB * 33];
    {
        const int4 v = reinterpret_cast<const int4*>(WC)[g * 256 + tid];
        const int n  = tid >> 3;
        const int e0 = (tid & 7) * 4;
        s_wc[n * 33 + e0 + 0] = (unsigned int)v.x;
        s_wc[n * 33 + e0 + 1] = (unsigned int)v.y;
        s_wc[n * 33 + e0 + 2] = (unsigned int)v.z;
        s_wc[n * 33 + e0 + 3] = (unsigned int)v.w;
    }
    __syncthreads();

    const int wave = tid >> 6;
    const int lane = tid & 63;
    const int nl   = wave * 8 + (lane >> 3);    // node-local 0..31
    const int l8   = lane & 7;                  // 4 cols of the 32-col slice
    const unsigned char* Gs = G + (size_t)chunk * SLICE_BYTES;

    float4 acc = make_float4(0.f, 0.f, 0.f, 0.f);
#pragma unroll
    for (int e = 0; e < EE; ++e) {
        const unsigned int wc = s_wc[nl * 33 + e];
        const unsigned int u  = *reinterpret_cast<const unsigned int*>(
            Gs + ((wc & 0xFFFFu) << 5) + l8 * 4);
        const float w = __half2float(__ushort_as_half((unsigned short)(wc >> 16)));
        const floatx2 lo = __builtin_amdgcn_cvt_pk_f32_fp8(u, false); // bytes 0,1
        const floatx2 hi = __builtin_amdgcn_cvt_pk_f32_fp8(u, true);  // bytes 2,3
        acc.x = fmaf(lo.x, w, acc.x);
        acc.y = fmaf(lo.y, w, acc.y);
        acc.z = fmaf(hi.x, w, acc.z);
        acc.w = fmaf(hi.y, w, acc.w);
    }

    float4 r;
    r.x = __logf(fmaxf(acc.x, 1e-10f));
    r.y = __logf(fmaxf(acc.y, 1e-10f));
    r.z = __logf(fmaxf(acc.z, 1e-10f));
    r.w = __logf(fmaxf(acc.w, 1e-10f));

    const int n   = g * NPB + nl;
    const int row = nids[n];
    *reinterpret_cast<float4*>(out + (size_t)row * BB + chunk * CHUNK_COLS + l8 * 4) = r;
}

// ---- fallback (ws too small): standalone fp32 version ----
__global__ __launch_bounds__(256, 2)
void sum_layer_fallback(const float* __restrict__ element_mars,
                        const float* __restrict__ params,
                        const int* __restrict__ nids,
                        const int* __restrict__ cids,
                        const int* __restrict__ pids,
                        float* __restrict__ out)
{
    const int tid  = threadIdx.x;
    const int wave = tid >> 6;
    const int lane = tid & 63;

    __shared__ int   s_cid[4][EE];
    __shared__ float s_w[4][EE];
    if (tid < 4 * EE) {
        const int wi = tid >> 5, e = tid & (EE - 1);
        const int gn = blockIdx.x * 4 + wi;
        s_cid[wi][e] = cids[gn * EE + e];
        s_w[wi][e]   = params[pids[gn * EE + e]];
    }
    __syncthreads();

    const int n = blockIdx.x * 4 + wave;
    float4 acc = make_float4(0.f, 0.f, 0.f, 0.f);
#pragma unroll
    for (int e = 0; e < EE; ++e) {
        const float4 v = *reinterpret_cast<const float4*>(
            element_mars + (size_t)s_cid[wave][e] * BB + 4 * lane);
        const float w = s_w[wave][e];
        acc.x = fmaf(__expf(v.x), w, acc.x);
        acc.y = fmaf(__expf(v.y), w, acc.y);
        acc.z = fmaf(__expf(v.z), w, acc.z);
        acc.w = fmaf(__expf(v.w), w, acc.w);
    }
    float4 r;
    r.x = __logf(fmaxf(acc.x, 1e-10f));
    r.y = __logf(fmaxf(acc.y, 1e-10f));
    r.z = __logf(fmaxf(acc.z, 1e-10f));
    r.w = __logf(fmaxf(acc.w, 1e-10f));
    *reinterpret_cast<float4*>(out + (size_t)nids[n] * BB + 4 * lane) = r;
}

extern "C" void kernel_launch(void* const* d_in, const int* in_sizes, int n_in,
                              void* d_out, int out_size, void* d_ws, size_t ws_size,
                              hipStream_t stream) {
    // inputs: node_mars[N,B], element_mars[MAX_ELS,B], params[N*E],
    //         nids[N], cids[N,E], pids[N,E]
    const float* element_mars = (const float*)d_in[1];
    const float* params       = (const float*)d_in[2];
    const int*   nids         = (const int*)d_in[3];
    const int*   cids         = (const int*)d_in[4];
    const int*   pids         = (const int*)d_in[5];
    float*       out          = (float*)d_out;

    const size_t g_bytes  = (size_t)NCHUNK * SLICE_BYTES;          // 16MB fp8
    const size_t wc_bytes = (size_t)NN * EE * sizeof(unsigned int); // 4MB

    if (ws_size >= g_bytes + wc_bytes) {
        unsigned char* G  = (unsigned char*)d_ws;
        unsigned int*  WC = (unsigned int*)((char*)d_ws + g_bytes);

        exp_convert_kernel<<<(MAX_ELS * BB / 16) / 256, 256, 0, stream>>>(
            (const float4*)element_mars, G);
        pack_wc_kernel<<<(NN * EE) / 256, 256, 0, stream>>>(params, cids, pids, WC);
        sum_main_kernel<<<(NN / NPB) * NCHUNK, 256, 0, stream>>>(G, WC, nids, out);
    } else {
        sum_layer_fallback<<<NN / 4, 256, 0, stream>>>(
            element_mars, params, nids, cids, pids, out);
    }
}